// Round 13
// baseline (307.233 us; speedup 1.0000x reference)
//
#include <hip/hip_runtime.h>
#include <hip/hip_bf16.h>

// Problem constants (fixed by reference)
#define Nn 16000
#define Ee 256000
#define Tt 5
#define GATES 512  // 4*LH
#define NREP 8     // one replica per XCD (XCC_ID-indexed)

typedef _Float16 f16;
typedef __attribute__((ext_vector_type(8))) _Float16 f16x8;
typedef __attribute__((ext_vector_type(4))) float f32x4;

// ---- workspace layout (float units) ----
#define OFF_DINV 0
#define OFF_AGG   (OFF_DINV + Nn)              // T*N fp32 final, time-major [t][n]
#define OFF_AGGR  (OFF_AGG + Nn*Tt)            // NREP*N*5 fp32 replicas (node-major per replica)
#define OFF_DEGR  (OFF_AGGR + NREP*Nn*Tt)      // NREP*N ints
#define OFF_B0    (OFF_DEGR + NREP*Nn)         // 512
#define OFF_B1    (OFF_B0 + GATES)             // 512
#define OFF_W0S   (OFF_B1 + GATES)             // 512*192 f16 (swizzled)
#define OFF_W1S   (OFF_W0S + 512*192/2)        // 512*256 f16 (swizzled)
#define OFF_PWS   (OFF_W1S + 512*256/2)        // 64*128 f16 (swizzled head weights)
#define OFF_END   (OFF_PWS + 64*128/2)

__device__ __forceinline__ float fsig(float x) { return 1.f / (1.f + __expf(-x)); }
__device__ __forceinline__ float ftanh(float x) { return 1.f - 2.f / (1.f + __expf(2.f * x)); }

__device__ __forceinline__ unsigned xcc_id() {
    unsigned x;
    asm volatile("s_getreg_b32 %0, hwreg(HW_REG_XCC_ID)" : "=s"(x));
    return x & (NREP - 1);
}

// ---- prep: swizzle weights, fold biases, zero deg replicas ----
// NEW B-frag swizzle (gate-contiguous): addr = ((g*NKT + kt)*4 + gate)*512 + (quad*16+l)*8 + j
// -> in the kernel the 4 gate loads share ONE address with 1024B immediate offsets
// (cuts hoisted-address VGPR pressure that drove R11's residual spill).
// q = gate*128 + g*16 + l ; k = kt*32 + quad*8 + j.
__global__ void prep_weights(const float* __restrict__ w_ih0, const float* __restrict__ w_hh0,
                             const float* __restrict__ b_ih0, const float* __restrict__ b_hh0,
                             const float* __restrict__ w_ih1, const float* __restrict__ w_hh1,
                             const float* __restrict__ b_ih1, const float* __restrict__ b_hh1,
                             const float* __restrict__ pw1,
                             f16* __restrict__ W0S, f16* __restrict__ W1S, f16* __restrict__ pwS,
                             float* __restrict__ B0, float* __restrict__ B1,
                             int* __restrict__ degr) {
    int b = blockIdx.x, t = threadIdx.x;
    if (b < 512) {
        if (t < 192) {
            int q = b, k = t;
            float v = (k < 64) ? w_ih0[q * 64 + k] : w_hh0[q * 128 + (k - 64)];
            int g = (q & 127) >> 4, l = q & 15, gate = q >> 7;
            int kt = k >> 5, quad = (k >> 3) & 3, j = k & 7;
            W0S[(((g * 6 + kt) * 4 + gate) * 64 + quad * 16 + l) * 8 + j] = (f16)v;
        }
    } else if (b < 1024) {
        int q = b - 512, k = t;
        float v = (k < 128) ? w_ih1[q * 128 + k] : w_hh1[q * 128 + (k - 128)];
        int g = (q & 127) >> 4, l = q & 15, gate = q >> 7;
        int kt = k >> 5, quad = (k >> 3) & 3, j = k & 7;
        W1S[(((g * 8 + kt) * 4 + gate) * 64 + quad * 16 + l) * 8 + j] = (f16)v;
    } else if (b < 1028) {
        int idx = (b - 1024) * 256 + t;
        if (idx < 512) B0[idx] = b_ih0[idx] + b_hh0[idx];
        else           B1[idx - 512] = b_ih1[idx - 512] + b_hh1[idx - 512];
    } else if (b < 1092) {
        if (t < 128) {
            int u = b - 1028, k = t;
            int g = u >> 4, lp = u & 15;
            int kt = k >> 5, quad = (k >> 3) & 3, j = k & 7;
            pwS[((g * 4 + kt) * 64 + quad * 16 + lp) * 8 + j] = (f16)pw1[u * 128 + k];
        }
    } else {
        int n = (b - 1092) * 256 + t;
        if (n < NREP * Nn) degr[n] = 0;
    }
}

// ---- degree count: XCD-local replica, workgroup-scope atomic (executes in local L2) ----
__global__ void deg_count(const int* __restrict__ ei, int* __restrict__ degr) {
    int e = blockIdx.x * blockDim.x + threadIdx.x;
    if (e >= Ee) return;
    int* p = &degr[xcc_id() * Nn + ei[Ee + e]];
    __hip_atomic_fetch_add(p, 1, __ATOMIC_RELAXED, __HIP_MEMORY_SCOPE_WORKGROUP);
}

// ---- dinv + init agg replicas (replica 0 = self-loop term, others 0) ----
__global__ void agg_init(const float* __restrict__ x, const int* __restrict__ degr,
                         float* __restrict__ dinv, float* __restrict__ aggr) {
    int n = blockIdx.x * blockDim.x + threadIdx.x;
    if (n >= Nn) return;
    int deg = 1;  // self loop
    #pragma unroll
    for (int r = 0; r < NREP; ++r) deg += degr[r * Nn + n];
    float di = rsqrtf((float)deg);
    dinv[n] = di;
    float dd = di * di;
    #pragma unroll
    for (int t = 0; t < Tt; ++t) aggr[n * Tt + t] = x[n * Tt + t] * dd;
    #pragma unroll
    for (int r = 1; r < NREP; ++r) {
        #pragma unroll
        for (int t = 0; t < Tt; ++t) aggr[r * (Nn * Tt) + n * Tt + t] = 0.f;
    }
}

// ---- edge scatter: one (edge,t) per thread; XCD-local replica, workgroup-scope atomic ----
__global__ void edge_scatter(const float* __restrict__ x, const int* __restrict__ ei,
                             const float* __restrict__ dinv, float* __restrict__ aggr) {
    int idx = blockIdx.x * blockDim.x + threadIdx.x;
    if (idx >= Ee * Tt) return;
    int e = idx / Tt, t = idx - e * Tt;
    int s = ei[e], d = ei[Ee + e];
    float v = x[s * Tt + t] * dinv[s] * dinv[d];
    float* p = aggr + (size_t)xcc_id() * (Nn * Tt) + (size_t)d * Tt + t;
    __hip_atomic_fetch_add(p, v, __ATOMIC_RELAXED, __HIP_MEMORY_SCOPE_WORKGROUP);
}

// ---- fold replicas -> final agg, transposed to [t][n] (coalesced reads in recur_all) ----
__global__ void agg_reduce(const float* __restrict__ aggr, float* __restrict__ agg) {
    int n = blockIdx.x * blockDim.x + threadIdx.x;
    if (n >= Nn) return;
    float s[Tt];
    #pragma unroll
    for (int t = 0; t < Tt; ++t) s[t] = 0.f;
    #pragma unroll
    for (int r = 0; r < NREP; ++r)
        #pragma unroll
        for (int t = 0; t < Tt; ++t) s[t] += aggr[r * (Nn * Tt) + n * Tt + t];
    #pragma unroll
    for (int t = 0; t < Tt; ++t) agg[t * Nn + n] = s[t];
}

// ---- fused recurrence: all 5 steps x 2 LSTM layers + head in ONE dispatch ----
// Block = 256 thr = 4 waves, 32 nodes. Wave = u32-group (2 u16 columns g2).
// ALLOCATOR LAW (R7/R8/R10/R11/R12): the compiler targets 2 blocks/CU ->
// VGPR cap = 512 / (2*waves_per_block/4): 256thr->256, 512thr->128, 1024thr->64.
// Only 256-thr blocks get 256 VGPRs. Demand here: acc[2][2][4]=64 + c 32 +
// af 8 + B-in-flight 32 + biases 16 + misc ~25 = ~175 < 256 -> NO spill.
// h0/h1 in LDS (16 KB), XOR-chunk swizzle (0 conflicts measured R7-R12).
// 2 blocks/CU co-resident: barrier drain of one overlaps compute of the other.
// t=0: h/c known zero -> skip those k-tiles and the c read.
__global__ __launch_bounds__(256, 1) void recur_all(
    const float* __restrict__ agg,
    const float* __restrict__ gw, const float* __restrict__ gb,
    const f16* __restrict__ W0S, const f16* __restrict__ W1S,
    const float* __restrict__ B0, const float* __restrict__ B1,
    const f16* __restrict__ pwS, const float* __restrict__ pb1,
    const float* __restrict__ pw2, const float* __restrict__ pb2,
    const float* __restrict__ x, float* __restrict__ out) {
    __shared__ f16 h0buf[32 * 128];
    __shared__ f16 h1buf[32 * 128];
    const int tid = threadIdx.x;
    const int lane = tid & 63;
    const int uw = tid >> 6;          // wave = u32-group (0..3)
    const int l = lane & 15;
    const int quad = lane >> 4;
    const int n0 = blockIdx.x * 32;

    // per-g2 hidden unit + biases
    float bI0[2], bF0[2], bG0[2], bO0[2], bI1[2], bF1[2], bG1[2], bO1[2];
    #pragma unroll
    for (int g2 = 0; g2 < 2; ++g2) {
        int u = (uw * 2 + g2) * 16 + l;
        bI0[g2] = B0[u]; bF0[g2] = B0[128 + u]; bG0[g2] = B0[256 + u]; bO0[g2] = B0[384 + u];
        bI1[g2] = B1[u]; bF1[g2] = B1[128 + u]; bG1[g2] = B1[256 + u]; bO1[g2] = B1[384 + u];
    }

    f32x4 c0s[2][2], c1s[2][2];
    #pragma unroll
    for (int i = 0; i < 2; ++i)
        #pragma unroll
        for (int g2 = 0; g2 < 2; ++g2) {
            c0s[i][g2] = (f32x4){0.f, 0.f, 0.f, 0.f};
            c1s[i][g2] = (f32x4){0.f, 0.f, 0.f, 0.f};
        }

    f32x4 acc[2][2][4];
    #pragma unroll 1
    for (int t = 0; t < Tt; ++t) {
        // ======== layer 0: K = [feat(64) | h0(128)], NKT=6 ========
        #pragma unroll
        for (int i = 0; i < 2; ++i)
            #pragma unroll
            for (int g2 = 0; g2 < 2; ++g2)
                #pragma unroll
                for (int g = 0; g < 4; ++g) acc[i][g2][g] = (f32x4){0.f, 0.f, 0.f, 0.f};
        float an[2];
        #pragma unroll
        for (int i = 0; i < 2; ++i)
            an[i] = agg[(size_t)t * Nn + n0 + i * 16 + l];

        #pragma unroll
        for (int kt = 0; kt < 6; ++kt) {
            if (kt >= 2 && t == 0) continue;       // h0 is zero at t=0
            f16x8 af[2];
            if (kt < 2) {
                #pragma unroll
                for (int j = 0; j < 8; ++j) {
                    int k = kt * 32 + quad * 8 + j;
                    float gwj = gw[k], gbj = gb[k];
                    #pragma unroll
                    for (int i = 0; i < 2; ++i)
                        af[i][j] = (f16)fmaxf(gwj * an[i] + gbj, 0.f);
                }
            } else {
                int ub = (kt - 2) * 4 + quad;      // h0 u-chunk
                #pragma unroll
                for (int i = 0; i < 2; ++i)
                    af[i] = *(const f16x8*)&h0buf[(i * 16 + l) * 128 + ((ub ^ l) << 3)];
            }
            #pragma unroll
            for (int g2 = 0; g2 < 2; ++g2) {
                const f16* bp = W0S + ((size_t)((uw * 2 + g2) * 6 + kt) * 4) * 512 + lane * 8;
                #pragma unroll
                for (int g = 0; g < 4; ++g) {
                    f16x8 b = *(const f16x8*)(bp + g * 512);   // 1024B imm offsets
                    #pragma unroll
                    for (int i = 0; i < 2; ++i)
                        acc[i][g2][g] = __builtin_amdgcn_mfma_f32_16x16x32_f16(af[i], b, acc[i][g2][g], 0, 0, 0);
                }
            }
        }
        __syncthreads();   // all waves done reading h0buf
        #pragma unroll
        for (int i = 0; i < 2; ++i)
            #pragma unroll
            for (int g2 = 0; g2 < 2; ++g2) {
                int u = (uw * 2 + g2) * 16 + l;
                int uch = u >> 3, ulo = u & 7;
                f32x4 cc = c0s[i][g2];
                #pragma unroll
                for (int r = 0; r < 4; ++r) {
                    float i_ = fsig(acc[i][g2][0][r] + bI0[g2]);
                    float f_ = fsig(acc[i][g2][1][r] + bF0[g2]);
                    float g_ = ftanh(acc[i][g2][2][r] + bG0[g2]);
                    float o_ = fsig(acc[i][g2][3][r] + bO0[g2]);
                    float cn = f_ * cc[r] + i_ * g_;
                    cc[r] = cn;
                    float hn = o_ * ftanh(cn);
                    int node = i * 16 + quad * 4 + r;
                    h0buf[node * 128 + (((uch ^ (node & 15)) << 3) | ulo)] = (f16)hn;
                }
                c0s[i][g2] = cc;
            }
        __syncthreads();   // new h0 visible

        // ======== layer 1: K = [h0(128) | h1(128)], NKT=8 ========
        #pragma unroll
        for (int i = 0; i < 2; ++i)
            #pragma unroll
            for (int g2 = 0; g2 < 2; ++g2)
                #pragma unroll
                for (int g = 0; g < 4; ++g) acc[i][g2][g] = (f32x4){0.f, 0.f, 0.f, 0.f};

        #pragma unroll
        for (int kt = 0; kt < 8; ++kt) {
            if (kt >= 4 && t == 0) continue;       // h1 is zero at t=0
            f16x8 af[2];
            const f16* hb = (kt < 4) ? h0buf : h1buf;
            int ub = (kt & 3) * 4 + quad;
            #pragma unroll
            for (int i = 0; i < 2; ++i)
                af[i] = *(const f16x8*)&hb[(i * 16 + l) * 128 + ((ub ^ l) << 3)];
            #pragma unroll
            for (int g2 = 0; g2 < 2; ++g2) {
                const f16* bp = W1S + ((size_t)((uw * 2 + g2) * 8 + kt) * 4) * 512 + lane * 8;
                #pragma unroll
                for (int g = 0; g < 4; ++g) {
                    f16x8 b = *(const f16x8*)(bp + g * 512);
                    #pragma unroll
                    for (int i = 0; i < 2; ++i)
                        acc[i][g2][g] = __builtin_amdgcn_mfma_f32_16x16x32_f16(af[i], b, acc[i][g2][g], 0, 0, 0);
                }
            }
        }
        __syncthreads();   // all waves done reading h1buf
        #pragma unroll
        for (int i = 0; i < 2; ++i)
            #pragma unroll
            for (int g2 = 0; g2 < 2; ++g2) {
                int u = (uw * 2 + g2) * 16 + l;
                int uch = u >> 3, ulo = u & 7;
                f32x4 cc = c1s[i][g2];
                #pragma unroll
                for (int r = 0; r < 4; ++r) {
                    float i_ = fsig(acc[i][g2][0][r] + bI1[g2]);
                    float f_ = fsig(acc[i][g2][1][r] + bF1[g2]);
                    float g_ = ftanh(acc[i][g2][2][r] + bG1[g2]);
                    float o_ = fsig(acc[i][g2][3][r] + bO1[g2]);
                    float cn = f_ * cc[r] + i_ * g_;
                    cc[r] = cn;
                    float hn = o_ * ftanh(cn);
                    int node = i * 16 + quad * 4 + r;
                    h1buf[node * 128 + (((uch ^ (node & 15)) << 3) | ulo)] = (f16)hn;
                }
                c1s[i][g2] = cc;
            }
        __syncthreads();   // new h1 visible
    }

    // ======== head: out = x[:,4] + relu(h1@pw1.T+pb1)@pw2.T + pb2 ========
    // waves 0..1 each handle one 16-node tile; A from LDS h1buf (swizzled)
    if (uw < 2) {
        f32x4 hacc[4];
        #pragma unroll
        for (int g = 0; g < 4; ++g) hacc[g] = (f32x4){0.f, 0.f, 0.f, 0.f};
        #pragma unroll
        for (int kt = 0; kt < 4; ++kt) {
            int ub = kt * 4 + quad;
            f16x8 a = *(const f16x8*)&h1buf[(uw * 16 + l) * 128 + ((ub ^ l) << 3)];
            #pragma unroll
            for (int g = 0; g < 4; ++g) {
                f16x8 b = *(const f16x8*)(pwS + (size_t)(g * 4 + kt) * 512 + lane * 8);
                hacc[g] = __builtin_amdgcn_mfma_f32_16x16x32_f16(a, b, hacc[g], 0, 0, 0);
            }
        }
        float yr[4] = {0.f, 0.f, 0.f, 0.f};
        #pragma unroll
        for (int g = 0; g < 4; ++g) {
            float pb = pb1[g * 16 + l];
            float pw = pw2[g * 16 + l];
            #pragma unroll
            for (int r = 0; r < 4; ++r)
                yr[r] += fmaxf(hacc[g][r] + pb, 0.f) * pw;
        }
        #pragma unroll
        for (int m = 1; m <= 8; m <<= 1) {
            #pragma unroll
            for (int r = 0; r < 4; ++r) yr[r] += __shfl_xor(yr[r], m);
        }
        if (l < 4) {
            float v = (l == 0) ? yr[0] : (l == 1) ? yr[1] : (l == 2) ? yr[2] : yr[3];
            int node = n0 + uw * 16 + quad * 4 + l;
            out[node] = x[node * Tt + (Tt - 1)] + v + pb2[0];
        }
    }
}

extern "C" void kernel_launch(void* const* d_in, const int* in_sizes, int n_in,
                              void* d_out, int out_size, void* d_ws, size_t ws_size,
                              hipStream_t stream) {
    const float* x      = (const float*)d_in[0];
    const int*   ei     = (const int*)d_in[1];
    const float* gcn_w  = (const float*)d_in[2];
    const float* gcn_b  = (const float*)d_in[3];
    const float* w_ih0  = (const float*)d_in[4];
    const float* w_hh0  = (const float*)d_in[5];
    const float* b_ih0  = (const float*)d_in[6];
    const float* b_hh0  = (const float*)d_in[7];
    const float* w_ih1  = (const float*)d_in[8];
    const float* w_hh1  = (const float*)d_in[9];
    const float* b_ih1  = (const float*)d_in[10];
    const float* b_hh1  = (const float*)d_in[11];
    const float* pw1    = (const float*)d_in[12];
    const float* pb1    = (const float*)d_in[13];
    const float* pw2    = (const float*)d_in[14];
    const float* pb2    = (const float*)d_in[15];
    float* out = (float*)d_out;

    float* wsf  = (float*)d_ws;
    float* dinv = wsf + OFF_DINV;
    float* agg  = wsf + OFF_AGG;
    float* aggr = wsf + OFF_AGGR;
    int*   degr = (int*)(wsf + OFF_DEGR);
    float* B0   = wsf + OFF_B0;
    float* B1   = wsf + OFF_B1;
    f16*   W0S  = (f16*)(wsf + OFF_W0S);
    f16*   W1S  = (f16*)(wsf + OFF_W1S);
    f16*   pwS  = (f16*)(wsf + OFF_PWS);

    // 1) prep weights (swizzled f16, incl. head pw1) + fold biases + zero deg replicas
    prep_weights<<<1592, 256, 0, stream>>>(w_ih0, w_hh0, b_ih0, b_hh0,
                                           w_ih1, w_hh1, b_ih1, b_hh1, pw1,
                                           W0S, W1S, pwS, B0, B1, degr);
    // 2) degree (XCD-local atomics)
    deg_count<<<(Ee + 255) / 256, 256, 0, stream>>>(ei, degr);
    // 3) dinv + agg replica init
    agg_init<<<(Nn + 255) / 256, 256, 0, stream>>>(x, degr, dinv, aggr);
    // 4) edge scatter: one (edge,t) per thread, XCD-local atomics
    edge_scatter<<<(Ee * Tt + 255) / 256, 256, 0, stream>>>(x, ei, dinv, aggr);
    // 5) fold replicas (+ transpose agg to [t][n])
    agg_reduce<<<(Nn + 255) / 256, 256, 0, stream>>>(aggr, agg);

    // 6) fused recurrence: all LSTM steps + head, one dispatch (4-wave, 32-node blocks)
    recur_all<<<Nn / 32, 256, 0, stream>>>(agg, gcn_w, gcn_b, W0S, W1S, B0, B1,
                                           pwS, pb1, pw2, pb2, x, out);
}

// Round 14
// 215.159 us; speedup vs baseline: 1.4279x; 1.4279x over previous
//
#include <hip/hip_runtime.h>
#include <hip/hip_bf16.h>

// Problem constants (fixed by reference)
#define Nn 16000
#define Ee 256000
#define Tt 5
#define GATES 512  // 4*LH
#define NREP 8     // one replica per XCD (XCC_ID-indexed)

typedef _Float16 f16;
typedef __attribute__((ext_vector_type(8))) _Float16 f16x8;
typedef __attribute__((ext_vector_type(4))) float f32x4;

// ---- workspace layout (float units) ----
#define OFF_DINV 0
#define OFF_AGG   (OFF_DINV + Nn)              // T*N fp32 final, time-major [t][n]
#define OFF_AGGR  (OFF_AGG + Nn*Tt)            // NREP*N*5 fp32 replicas (node-major per replica)
#define OFF_DEGR  (OFF_AGGR + NREP*Nn*Tt)      // NREP*N ints
#define OFF_B0    (OFF_DEGR + NREP*Nn)         // 512
#define OFF_B1    (OFF_B0 + GATES)             // 512
#define OFF_W0S   (OFF_B1 + GATES)             // 512*192 f16 (swizzled)
#define OFF_W1S   (OFF_W0S + 512*192/2)        // 512*256 f16 (swizzled)
#define OFF_PWS   (OFF_W1S + 512*256/2)        // 64*128 f16 (swizzled head weights)
#define OFF_END   (OFF_PWS + 64*128/2)

__device__ __forceinline__ float fsig(float x) { return 1.f / (1.f + __expf(-x)); }
__device__ __forceinline__ float ftanh(float x) { return 1.f - 2.f / (1.f + __expf(2.f * x)); }

__device__ __forceinline__ unsigned xcc_id() {
    unsigned x;
    asm volatile("s_getreg_b32 %0, hwreg(HW_REG_XCC_ID)" : "=s"(x));
    return x & (NREP - 1);
}

// ---- prep: swizzle weights, fold biases, zero deg replicas ----
// Gate-contiguous B-frag swizzle: addr = ((g*NKT + kt)*4 + gate)*512 + (quad*16+l)*8 + j
// -> kernel gate loads share ONE base with 1024B immediate offsets.
// q = gate*128 + g*16 + l ; k = kt*32 + quad*8 + j.
__global__ void prep_weights(const float* __restrict__ w_ih0, const float* __restrict__ w_hh0,
                             const float* __restrict__ b_ih0, const float* __restrict__ b_hh0,
                             const float* __restrict__ w_ih1, const float* __restrict__ w_hh1,
                             const float* __restrict__ b_ih1, const float* __restrict__ b_hh1,
                             const float* __restrict__ pw1,
                             f16* __restrict__ W0S, f16* __restrict__ W1S, f16* __restrict__ pwS,
                             float* __restrict__ B0, float* __restrict__ B1,
                             int* __restrict__ degr) {
    int b = blockIdx.x, t = threadIdx.x;
    if (b < 512) {
        if (t < 192) {
            int q = b, k = t;
            float v = (k < 64) ? w_ih0[q * 64 + k] : w_hh0[q * 128 + (k - 64)];
            int g = (q & 127) >> 4, l = q & 15, gate = q >> 7;
            int kt = k >> 5, quad = (k >> 3) & 3, j = k & 7;
            W0S[(((g * 6 + kt) * 4 + gate) * 64 + quad * 16 + l) * 8 + j] = (f16)v;
        }
    } else if (b < 1024) {
        int q = b - 512, k = t;
        float v = (k < 128) ? w_ih1[q * 128 + k] : w_hh1[q * 128 + (k - 128)];
        int g = (q & 127) >> 4, l = q & 15, gate = q >> 7;
        int kt = k >> 5, quad = (k >> 3) & 3, j = k & 7;
        W1S[(((g * 8 + kt) * 4 + gate) * 64 + quad * 16 + l) * 8 + j] = (f16)v;
    } else if (b < 1028) {
        int idx = (b - 1024) * 256 + t;
        if (idx < 512) B0[idx] = b_ih0[idx] + b_hh0[idx];
        else           B1[idx - 512] = b_ih1[idx - 512] + b_hh1[idx - 512];
    } else if (b < 1092) {
        if (t < 128) {
            int u = b - 1028, k = t;
            int g = u >> 4, lp = u & 15;
            int kt = k >> 5, quad = (k >> 3) & 3, j = k & 7;
            pwS[((g * 4 + kt) * 64 + quad * 16 + lp) * 8 + j] = (f16)pw1[u * 128 + k];
        }
    } else {
        int n = (b - 1092) * 256 + t;
        if (n < NREP * Nn) degr[n] = 0;
    }
}

// ---- degree count: XCD-local replica, workgroup-scope atomic (executes in local L2) ----
__global__ void deg_count(const int* __restrict__ ei, int* __restrict__ degr) {
    int e = blockIdx.x * blockDim.x + threadIdx.x;
    if (e >= Ee) return;
    int* p = &degr[xcc_id() * Nn + ei[Ee + e]];
    __hip_atomic_fetch_add(p, 1, __ATOMIC_RELAXED, __HIP_MEMORY_SCOPE_WORKGROUP);
}

// ---- dinv + init agg replicas (replica 0 = self-loop term, others 0) ----
__global__ void agg_init(const float* __restrict__ x, const int* __restrict__ degr,
                         float* __restrict__ dinv, float* __restrict__ aggr) {
    int n = blockIdx.x * blockDim.x + threadIdx.x;
    if (n >= Nn) return;
    int deg = 1;  // self loop
    #pragma unroll
    for (int r = 0; r < NREP; ++r) deg += degr[r * Nn + n];
    float di = rsqrtf((float)deg);
    dinv[n] = di;
    float dd = di * di;
    #pragma unroll
    for (int t = 0; t < Tt; ++t) aggr[n * Tt + t] = x[n * Tt + t] * dd;
    #pragma unroll
    for (int r = 1; r < NREP; ++r) {
        #pragma unroll
        for (int t = 0; t < Tt; ++t) aggr[r * (Nn * Tt) + n * Tt + t] = 0.f;
    }
}

// ---- edge scatter: one (edge,t) per thread; XCD-local replica, workgroup-scope atomic ----
__global__ void edge_scatter(const float* __restrict__ x, const int* __restrict__ ei,
                             const float* __restrict__ dinv, float* __restrict__ aggr) {
    int idx = blockIdx.x * blockDim.x + threadIdx.x;
    if (idx >= Ee * Tt) return;
    int e = idx / Tt, t = idx - e * Tt;
    int s = ei[e], d = ei[Ee + e];
    float v = x[s * Tt + t] * dinv[s] * dinv[d];
    float* p = aggr + (size_t)xcc_id() * (Nn * Tt) + (size_t)d * Tt + t;
    __hip_atomic_fetch_add(p, v, __ATOMIC_RELAXED, __HIP_MEMORY_SCOPE_WORKGROUP);
}

// ---- fold replicas -> final agg, transposed to [t][n] (coalesced reads in recur_all) ----
__global__ void agg_reduce(const float* __restrict__ aggr, float* __restrict__ agg) {
    int n = blockIdx.x * blockDim.x + threadIdx.x;
    if (n >= Nn) return;
    float s[Tt];
    #pragma unroll
    for (int t = 0; t < Tt; ++t) s[t] = 0.f;
    #pragma unroll
    for (int r = 0; r < NREP; ++r)
        #pragma unroll
        for (int t = 0; t < Tt; ++t) s[t] += aggr[r * (Nn * Tt) + n * Tt + t];
    #pragma unroll
    for (int t = 0; t < Tt; ++t) agg[t * Nn + n] = s[t];
}

// ---- fused recurrence: all 5 steps x 2 LSTM layers + head in ONE dispatch ----
// Block = 512 thr = 8 waves, 32 nodes = R11's best-known config (128 µs).
// SPILL ROOT CAUSE (R11 34MB@128, R13 48MB@256): fully-unrolled kt loops let
// the scheduler hoist 24-32 B-loads (4 VGPR each) -> demand expands to exceed
// ANY allocation. Fix: #pragma unroll 1 on LDS-fed kt loops caps transient
// regs at ~32/iter; persistent state ~70 -> demand ~100 < 128. TLP (4 waves/
// SIMD) hides the serialized-load latency.
// Gate-contiguous W swizzle: 4 gate loads share one base (+0/1/2/3 KB imm).
// h0/h1 in LDS (16 KB), XOR-chunk swizzle (0 conflicts measured R7-R13).
__global__ __launch_bounds__(512, 2) void recur_all(
    const float* __restrict__ agg,
    const float* __restrict__ gw, const float* __restrict__ gb,
    const f16* __restrict__ W0S, const f16* __restrict__ W1S,
    const float* __restrict__ B0, const float* __restrict__ B1,
    const f16* __restrict__ pwS, const float* __restrict__ pb1,
    const float* __restrict__ pw2, const float* __restrict__ pb2,
    const float* __restrict__ x, float* __restrict__ out) {
    __shared__ f16 h0buf[32 * 128];
    __shared__ f16 h1buf[32 * 128];
    const int tid = threadIdx.x;
    const int lane = tid & 63;
    const int uq = tid >> 6;          // wave = u16-group (0..7)
    const int l = lane & 15;
    const int quad = lane >> 4;
    const int n0 = blockIdx.x * 32;
    const int u = uq * 16 + l;        // this lane's hidden unit
    const int uch = u >> 3;           // u-chunk for LDS swizzle
    const int ulo = u & 7;

    const float bI0 = B0[u], bF0 = B0[128 + u], bG0 = B0[256 + u], bO0 = B0[384 + u];
    const float bI1 = B1[u], bF1 = B1[128 + u], bG1 = B1[256 + u], bO1 = B1[384 + u];

    f32x4 c0s[2], c1s[2];
    #pragma unroll
    for (int i = 0; i < 2; ++i) {
        c0s[i] = (f32x4){0.f, 0.f, 0.f, 0.f};
        c1s[i] = (f32x4){0.f, 0.f, 0.f, 0.f};
    }

    f32x4 acc[2][4];
    #pragma unroll 1
    for (int t = 0; t < Tt; ++t) {
        // ======== layer 0: K = [feat(64) | h0(128)], NKT=6 ========
        #pragma unroll
        for (int i = 0; i < 2; ++i)
            #pragma unroll
            for (int g = 0; g < 4; ++g) acc[i][g] = (f32x4){0.f, 0.f, 0.f, 0.f};
        float an[2];
        #pragma unroll
        for (int i = 0; i < 2; ++i)
            an[i] = agg[(size_t)t * Nn + n0 + i * 16 + l];

        // feat k-tiles (kt = 0,1): generated GCN features
        #pragma unroll
        for (int kt = 0; kt < 2; ++kt) {
            f16x8 af[2];
            #pragma unroll
            for (int j = 0; j < 8; ++j) {
                int k = kt * 32 + quad * 8 + j;
                float gwj = gw[k], gbj = gb[k];
                #pragma unroll
                for (int i = 0; i < 2; ++i)
                    af[i][j] = (f16)fmaxf(gwj * an[i] + gbj, 0.f);
            }
            const f16* bp = W0S + ((size_t)(uq * 6 + kt) * 4) * 512 + lane * 8;
            #pragma unroll
            for (int g = 0; g < 4; ++g) {
                f16x8 b = *(const f16x8*)(bp + g * 512);
                #pragma unroll
                for (int i = 0; i < 2; ++i)
                    acc[i][g] = __builtin_amdgcn_mfma_f32_16x16x32_f16(af[i], b, acc[i][g], 0, 0, 0);
            }
        }
        // h0 k-tiles (kt = 2..5): skip at t=0 (h0 zero). unroll 1 caps load hoisting.
        if (t > 0) {
            #pragma unroll 1
            for (int kt = 2; kt < 6; ++kt) {
                int ub = (kt - 2) * 4 + quad;      // h0 u-chunk
                f16x8 af[2];
                #pragma unroll
                for (int i = 0; i < 2; ++i)
                    af[i] = *(const f16x8*)&h0buf[(i * 16 + l) * 128 + ((ub ^ l) << 3)];
                const f16* bp = W0S + ((size_t)(uq * 6 + kt) * 4) * 512 + lane * 8;
                #pragma unroll
                for (int g = 0; g < 4; ++g) {
                    f16x8 b = *(const f16x8*)(bp + g * 512);
                    #pragma unroll
                    for (int i = 0; i < 2; ++i)
                        acc[i][g] = __builtin_amdgcn_mfma_f32_16x16x32_f16(af[i], b, acc[i][g], 0, 0, 0);
                }
            }
        }
        __syncthreads();   // all waves done reading h0buf
        #pragma unroll
        for (int i = 0; i < 2; ++i) {
            f32x4 cc = c0s[i];
            #pragma unroll
            for (int r = 0; r < 4; ++r) {
                float i_ = fsig(acc[i][0][r] + bI0);
                float f_ = fsig(acc[i][1][r] + bF0);
                float g_ = ftanh(acc[i][2][r] + bG0);
                float o_ = fsig(acc[i][3][r] + bO0);
                float cn = f_ * cc[r] + i_ * g_;
                cc[r] = cn;
                float hn = o_ * ftanh(cn);
                int node = i * 16 + quad * 4 + r;
                h0buf[node * 128 + (((uch ^ (node & 15)) << 3) | ulo)] = (f16)hn;
            }
            c0s[i] = cc;
        }
        __syncthreads();   // new h0 visible

        // ======== layer 1: K = [h0(128) | h1(128)], NKT=8 ========
        #pragma unroll
        for (int i = 0; i < 2; ++i)
            #pragma unroll
            for (int g = 0; g < 4; ++g) acc[i][g] = (f32x4){0.f, 0.f, 0.f, 0.f};

        {
            int ktmax = (t == 0) ? 4 : 8;          // h1 zero at t=0
            #pragma unroll 1
            for (int kt = 0; kt < ktmax; ++kt) {
                const f16* hb = (kt < 4) ? h0buf : h1buf;
                int ub = (kt & 3) * 4 + quad;
                f16x8 af[2];
                #pragma unroll
                for (int i = 0; i < 2; ++i)
                    af[i] = *(const f16x8*)&hb[(i * 16 + l) * 128 + ((ub ^ l) << 3)];
                const f16* bp = W1S + ((size_t)(uq * 8 + kt) * 4) * 512 + lane * 8;
                #pragma unroll
                for (int g = 0; g < 4; ++g) {
                    f16x8 b = *(const f16x8*)(bp + g * 512);
                    #pragma unroll
                    for (int i = 0; i < 2; ++i)
                        acc[i][g] = __builtin_amdgcn_mfma_f32_16x16x32_f16(af[i], b, acc[i][g], 0, 0, 0);
                }
            }
        }
        __syncthreads();   // all waves done reading h1buf
        #pragma unroll
        for (int i = 0; i < 2; ++i) {
            f32x4 cc = c1s[i];
            #pragma unroll
            for (int r = 0; r < 4; ++r) {
                float i_ = fsig(acc[i][0][r] + bI1);
                float f_ = fsig(acc[i][1][r] + bF1);
                float g_ = ftanh(acc[i][2][r] + bG1);
                float o_ = fsig(acc[i][3][r] + bO1);
                float cn = f_ * cc[r] + i_ * g_;
                cc[r] = cn;
                float hn = o_ * ftanh(cn);
                int node = i * 16 + quad * 4 + r;
                h1buf[node * 128 + (((uch ^ (node & 15)) << 3) | ulo)] = (f16)hn;
            }
            c1s[i] = cc;
        }
        __syncthreads();   // new h1 visible
    }

    // ======== head: out = x[:,4] + relu(h1@pw1.T+pb1)@pw2.T + pb2 ========
    // waves 0..1 each handle one 16-node tile; A from LDS h1buf (swizzled)
    if (uq < 2) {
        f32x4 hacc[4];
        #pragma unroll
        for (int g = 0; g < 4; ++g) hacc[g] = (f32x4){0.f, 0.f, 0.f, 0.f};
        #pragma unroll
        for (int kt = 0; kt < 4; ++kt) {
            int ub = kt * 4 + quad;
            f16x8 a = *(const f16x8*)&h1buf[(uq * 16 + l) * 128 + ((ub ^ l) << 3)];
            #pragma unroll
            for (int g = 0; g < 4; ++g) {
                f16x8 b = *(const f16x8*)(pwS + (size_t)(g * 4 + kt) * 512 + lane * 8);
                hacc[g] = __builtin_amdgcn_mfma_f32_16x16x32_f16(a, b, hacc[g], 0, 0, 0);
            }
        }
        float yr[4] = {0.f, 0.f, 0.f, 0.f};
        #pragma unroll
        for (int g = 0; g < 4; ++g) {
            float pb = pb1[g * 16 + l];
            float pw = pw2[g * 16 + l];
            #pragma unroll
            for (int r = 0; r < 4; ++r)
                yr[r] += fmaxf(hacc[g][r] + pb, 0.f) * pw;
        }
        #pragma unroll
        for (int m = 1; m <= 8; m <<= 1) {
            #pragma unroll
            for (int r = 0; r < 4; ++r) yr[r] += __shfl_xor(yr[r], m);
        }
        if (l < 4) {
            float v = (l == 0) ? yr[0] : (l == 1) ? yr[1] : (l == 2) ? yr[2] : yr[3];
            int node = n0 + uq * 16 + quad * 4 + l;
            out[node] = x[node * Tt + (Tt - 1)] + v + pb2[0];
        }
    }
}

extern "C" void kernel_launch(void* const* d_in, const int* in_sizes, int n_in,
                              void* d_out, int out_size, void* d_ws, size_t ws_size,
                              hipStream_t stream) {
    const float* x      = (const float*)d_in[0];
    const int*   ei     = (const int*)d_in[1];
    const float* gcn_w  = (const float*)d_in[2];
    const float* gcn_b  = (const float*)d_in[3];
    const float* w_ih0  = (const float*)d_in[4];
    const float* w_hh0  = (const float*)d_in[5];
    const float* b_ih0  = (const float*)d_in[6];
    const float* b_hh0  = (const float*)d_in[7];
    const float* w_ih1  = (const float*)d_in[8];
    const float* w_hh1  = (const float*)d_in[9];
    const float* b_ih1  = (const float*)d_in[10];
    const float* b_hh1  = (const float*)d_in[11];
    const float* pw1    = (const float*)d_in[12];
    const float* pb1    = (const float*)d_in[13];
    const float* pw2    = (const float*)d_in[14];
    const float* pb2    = (const float*)d_in[15];
    float* out = (float*)d_out;

    float* wsf  = (float*)d_ws;
    float* dinv = wsf + OFF_DINV;
    float* agg  = wsf + OFF_AGG;
    float* aggr = wsf + OFF_AGGR;
    int*   degr = (int*)(wsf + OFF_DEGR);
    float* B0   = wsf + OFF_B0;
    float* B1   = wsf + OFF_B1;
    f16*   W0S  = (f16*)(wsf + OFF_W0S);
    f16*   W1S  = (f16*)(wsf + OFF_W1S);
    f16*   pwS  = (f16*)(wsf + OFF_PWS);

    // 1) prep weights (swizzled f16, incl. head pw1) + fold biases + zero deg replicas
    prep_weights<<<1592, 256, 0, stream>>>(w_ih0, w_hh0, b_ih0, b_hh0,
                                           w_ih1, w_hh1, b_ih1, b_hh1, pw1,
                                           W0S, W1S, pwS, B0, B1, degr);
    // 2) degree (XCD-local atomics)
    deg_count<<<(Ee + 255) / 256, 256, 0, stream>>>(ei, degr);
    // 3) dinv + agg replica init
    agg_init<<<(Nn + 255) / 256, 256, 0, stream>>>(x, degr, dinv, aggr);
    // 4) edge scatter: one (edge,t) per thread, XCD-local atomics
    edge_scatter<<<(Ee * Tt + 255) / 256, 256, 0, stream>>>(x, ei, dinv, aggr);
    // 5) fold replicas (+ transpose agg to [t][n])
    agg_reduce<<<(Nn + 255) / 256, 256, 0, stream>>>(aggr, agg);

    // 6) fused recurrence: all LSTM steps + head, one dispatch (8-wave, 32-node blocks)
    recur_all<<<Nn / 32, 512, 0, stream>>>(agg, gcn_w, gcn_b, W0S, W1S, B0, B1,
                                           pwS, pb1, pw2, pb2, x, out);
}

// Round 15
// 208.033 us; speedup vs baseline: 1.4769x; 1.0343x over previous
//
#include <hip/hip_runtime.h>
#include <hip/hip_bf16.h>

// Problem constants (fixed by reference)
#define Nn 16000
#define Ee 256000
#define Tt 5
#define GATES 512  // 4*LH
#define NREP 8     // one replica per XCD (XCC_ID-indexed)

typedef _Float16 f16;
typedef __attribute__((ext_vector_type(8))) _Float16 f16x8;
typedef __attribute__((ext_vector_type(4))) float f32x4;

// ---- workspace layout (float units) ----
#define OFF_DINV 0
#define OFF_AGG   (OFF_DINV + Nn)              // T*N fp32 final, time-major [t][n]
#define OFF_AGGR  (OFF_AGG + Nn*Tt)            // NREP*N*5 fp32 replicas (node-major per replica)
#define OFF_DEGR  (OFF_AGGR + NREP*Nn*Tt)      // NREP*N ints
#define OFF_B0    (OFF_DEGR + NREP*Nn)         // 512
#define OFF_B1    (OFF_B0 + GATES)             // 512
#define OFF_W0S   (OFF_B1 + GATES)             // 512*192 f16 (swizzled)
#define OFF_W1S   (OFF_W0S + 512*192/2)        // 512*256 f16 (swizzled)
#define OFF_PWS   (OFF_W1S + 512*256/2)        // 64*128 f16 (swizzled head weights)
#define OFF_END   (OFF_PWS + 64*128/2)

__device__ __forceinline__ float fsig(float x) { return 1.f / (1.f + __expf(-x)); }
__device__ __forceinline__ float ftanh(float x) { return 1.f - 2.f / (1.f + __expf(2.f * x)); }

__device__ __forceinline__ unsigned xcc_id() {
    unsigned x;
    asm volatile("s_getreg_b32 %0, hwreg(HW_REG_XCC_ID)" : "=s"(x));
    return x & (NREP - 1);
}

// ---- prep: swizzle weights, fold biases, zero deg replicas ----
// Gate-contiguous B-frag swizzle: addr = ((g*NKT + kt)*4 + gate)*512 + (quad*16+l)*8 + j
// -> kernel gate loads share ONE base with 1024B immediate offsets.
// q = gate*128 + g*16 + l ; k = kt*32 + quad*8 + j.
__global__ void prep_weights(const float* __restrict__ w_ih0, const float* __restrict__ w_hh0,
                             const float* __restrict__ b_ih0, const float* __restrict__ b_hh0,
                             const float* __restrict__ w_ih1, const float* __restrict__ w_hh1,
                             const float* __restrict__ b_ih1, const float* __restrict__ b_hh1,
                             const float* __restrict__ pw1,
                             f16* __restrict__ W0S, f16* __restrict__ W1S, f16* __restrict__ pwS,
                             float* __restrict__ B0, float* __restrict__ B1,
                             int* __restrict__ degr) {
    int b = blockIdx.x, t = threadIdx.x;
    if (b < 512) {
        if (t < 192) {
            int q = b, k = t;
            float v = (k < 64) ? w_ih0[q * 64 + k] : w_hh0[q * 128 + (k - 64)];
            int g = (q & 127) >> 4, l = q & 15, gate = q >> 7;
            int kt = k >> 5, quad = (k >> 3) & 3, j = k & 7;
            W0S[(((g * 6 + kt) * 4 + gate) * 64 + quad * 16 + l) * 8 + j] = (f16)v;
        }
    } else if (b < 1024) {
        int q = b - 512, k = t;
        float v = (k < 128) ? w_ih1[q * 128 + k] : w_hh1[q * 128 + (k - 128)];
        int g = (q & 127) >> 4, l = q & 15, gate = q >> 7;
        int kt = k >> 5, quad = (k >> 3) & 3, j = k & 7;
        W1S[(((g * 8 + kt) * 4 + gate) * 64 + quad * 16 + l) * 8 + j] = (f16)v;
    } else if (b < 1028) {
        int idx = (b - 1024) * 256 + t;
        if (idx < 512) B0[idx] = b_ih0[idx] + b_hh0[idx];
        else           B1[idx - 512] = b_ih1[idx - 512] + b_hh1[idx - 512];
    } else if (b < 1092) {
        if (t < 128) {
            int u = b - 1028, k = t;
            int g = u >> 4, lp = u & 15;
            int kt = k >> 5, quad = (k >> 3) & 3, j = k & 7;
            pwS[((g * 4 + kt) * 64 + quad * 16 + lp) * 8 + j] = (f16)pw1[u * 128 + k];
        }
    } else {
        int n = (b - 1092) * 256 + t;
        if (n < NREP * Nn) degr[n] = 0;
    }
}

// ---- degree count: XCD-local replica, workgroup-scope atomic (executes in local L2) ----
__global__ void deg_count(const int* __restrict__ ei, int* __restrict__ degr) {
    int e = blockIdx.x * blockDim.x + threadIdx.x;
    if (e >= Ee) return;
    int* p = &degr[xcc_id() * Nn + ei[Ee + e]];
    __hip_atomic_fetch_add(p, 1, __ATOMIC_RELAXED, __HIP_MEMORY_SCOPE_WORKGROUP);
}

// ---- dinv + init agg replicas (replica 0 = self-loop term, others 0) ----
__global__ void agg_init(const float* __restrict__ x, const int* __restrict__ degr,
                         float* __restrict__ dinv, float* __restrict__ aggr) {
    int n = blockIdx.x * blockDim.x + threadIdx.x;
    if (n >= Nn) return;
    int deg = 1;  // self loop
    #pragma unroll
    for (int r = 0; r < NREP; ++r) deg += degr[r * Nn + n];
    float di = rsqrtf((float)deg);
    dinv[n] = di;
    float dd = di * di;
    #pragma unroll
    for (int t = 0; t < Tt; ++t) aggr[n * Tt + t] = x[n * Tt + t] * dd;
    #pragma unroll
    for (int r = 1; r < NREP; ++r) {
        #pragma unroll
        for (int t = 0; t < Tt; ++t) aggr[r * (Nn * Tt) + n * Tt + t] = 0.f;
    }
}

// ---- edge scatter: one (edge,t) per thread; XCD-local replica, workgroup-scope atomic ----
__global__ void edge_scatter(const float* __restrict__ x, const int* __restrict__ ei,
                             const float* __restrict__ dinv, float* __restrict__ aggr) {
    int idx = blockIdx.x * blockDim.x + threadIdx.x;
    if (idx >= Ee * Tt) return;
    int e = idx / Tt, t = idx - e * Tt;
    int s = ei[e], d = ei[Ee + e];
    float v = x[s * Tt + t] * dinv[s] * dinv[d];
    float* p = aggr + (size_t)xcc_id() * (Nn * Tt) + (size_t)d * Tt + t;
    __hip_atomic_fetch_add(p, v, __ATOMIC_RELAXED, __HIP_MEMORY_SCOPE_WORKGROUP);
}

// ---- fold replicas -> final agg, transposed to [t][n] (coalesced reads in recur_all) ----
__global__ void agg_reduce(const float* __restrict__ aggr, float* __restrict__ agg) {
    int n = blockIdx.x * blockDim.x + threadIdx.x;
    if (n >= Nn) return;
    float s[Tt];
    #pragma unroll
    for (int t = 0; t < Tt; ++t) s[t] = 0.f;
    #pragma unroll
    for (int r = 0; r < NREP; ++r)
        #pragma unroll
        for (int t = 0; t < Tt; ++t) s[t] += aggr[r * (Nn * Tt) + n * Tt + t];
    #pragma unroll
    for (int t = 0; t < Tt; ++t) agg[t * Nn + n] = s[t];
}

// ---- fused recurrence: all 5 steps x 2 LSTM layers + head in ONE dispatch ----
// Block = 512 thr = 8 waves, 32 nodes (R14's spill-free config: VGPR 88,
// WRITE 62 KB). R14 counters: VALU 55%, Mfma 13%, 20 barriers -> latency-bound.
// This round: (1) ping-pong h0/h1 (removes WAR hazards -> 2 barriers/step,
// was 4); (2) unroll 2 on LDS kt loops (2x loads in flight; transient +32 reg
// -> demand ~118 < 128 — revert if WRITE_SIZE regresses).
// Gate-contiguous W swizzle: 4 gate loads share one base (+0/1/2/3 KB imm).
// XOR-chunk h swizzle: 0 LDS bank conflicts (measured R7-R14).
__global__ __launch_bounds__(512, 2) void recur_all(
    const float* __restrict__ agg,
    const float* __restrict__ gw, const float* __restrict__ gb,
    const f16* __restrict__ W0S, const f16* __restrict__ W1S,
    const float* __restrict__ B0, const float* __restrict__ B1,
    const f16* __restrict__ pwS, const float* __restrict__ pb1,
    const float* __restrict__ pw2, const float* __restrict__ pb2,
    const float* __restrict__ x, float* __restrict__ out) {
    __shared__ f16 h0buf[2][32 * 128];   // ping-pong
    __shared__ f16 h1buf[2][32 * 128];
    const int tid = threadIdx.x;
    const int lane = tid & 63;
    const int uq = tid >> 6;          // wave = u16-group (0..7)
    const int l = lane & 15;
    const int quad = lane >> 4;
    const int n0 = blockIdx.x * 32;
    const int u = uq * 16 + l;        // this lane's hidden unit
    const int uch = u >> 3;           // u-chunk for LDS swizzle
    const int ulo = u & 7;

    const float bI0 = B0[u], bF0 = B0[128 + u], bG0 = B0[256 + u], bO0 = B0[384 + u];
    const float bI1 = B1[u], bF1 = B1[128 + u], bG1 = B1[256 + u], bO1 = B1[384 + u];

    f32x4 c0s[2], c1s[2];
    #pragma unroll
    for (int i = 0; i < 2; ++i) {
        c0s[i] = (f32x4){0.f, 0.f, 0.f, 0.f};
        c1s[i] = (f32x4){0.f, 0.f, 0.f, 0.f};
    }

    f32x4 acc[2][4];
    #pragma unroll 1
    for (int t = 0; t < Tt; ++t) {
        const int cur = t & 1;        // read h[cur], write h[cur^1]
        const f16* h0r = h0buf[cur];
        const f16* h1r = h1buf[cur];
        f16* h0w = h0buf[cur ^ 1];
        f16* h1w = h1buf[cur ^ 1];

        // ======== layer 0: K = [feat(64) | h0(128)], NKT=6 ========
        #pragma unroll
        for (int i = 0; i < 2; ++i)
            #pragma unroll
            for (int g = 0; g < 4; ++g) acc[i][g] = (f32x4){0.f, 0.f, 0.f, 0.f};
        float an[2];
        #pragma unroll
        for (int i = 0; i < 2; ++i)
            an[i] = agg[(size_t)t * Nn + n0 + i * 16 + l];

        // feat k-tiles (kt = 0,1): generated GCN features
        #pragma unroll
        for (int kt = 0; kt < 2; ++kt) {
            f16x8 af[2];
            #pragma unroll
            for (int j = 0; j < 8; ++j) {
                int k = kt * 32 + quad * 8 + j;
                float gwj = gw[k], gbj = gb[k];
                #pragma unroll
                for (int i = 0; i < 2; ++i)
                    af[i][j] = (f16)fmaxf(gwj * an[i] + gbj, 0.f);
            }
            const f16* bp = W0S + ((size_t)(uq * 6 + kt) * 4) * 512 + lane * 8;
            #pragma unroll
            for (int g = 0; g < 4; ++g) {
                f16x8 b = *(const f16x8*)(bp + g * 512);
                #pragma unroll
                for (int i = 0; i < 2; ++i)
                    acc[i][g] = __builtin_amdgcn_mfma_f32_16x16x32_f16(af[i], b, acc[i][g], 0, 0, 0);
            }
        }
        // h0 k-tiles (kt = 2..5): skip at t=0 (h0 zero). unroll 2: 2x loads in flight.
        if (t > 0) {
            #pragma unroll 2
            for (int kt = 2; kt < 6; ++kt) {
                int ub = (kt - 2) * 4 + quad;      // h0 u-chunk
                f16x8 af[2];
                #pragma unroll
                for (int i = 0; i < 2; ++i)
                    af[i] = *(const f16x8*)&h0r[(i * 16 + l) * 128 + ((ub ^ l) << 3)];
                const f16* bp = W0S + ((size_t)(uq * 6 + kt) * 4) * 512 + lane * 8;
                #pragma unroll
                for (int g = 0; g < 4; ++g) {
                    f16x8 b = *(const f16x8*)(bp + g * 512);
                    #pragma unroll
                    for (int i = 0; i < 2; ++i)
                        acc[i][g] = __builtin_amdgcn_mfma_f32_16x16x32_f16(af[i], b, acc[i][g], 0, 0, 0);
                }
            }
        }
        // L0 epilogue -> write h0_new into the OTHER buffer (no WAR with readers)
        #pragma unroll
        for (int i = 0; i < 2; ++i) {
            f32x4 cc = c0s[i];
            #pragma unroll
            for (int r = 0; r < 4; ++r) {
                float i_ = fsig(acc[i][0][r] + bI0);
                float f_ = fsig(acc[i][1][r] + bF0);
                float g_ = ftanh(acc[i][2][r] + bG0);
                float o_ = fsig(acc[i][3][r] + bO0);
                float cn = f_ * cc[r] + i_ * g_;
                cc[r] = cn;
                float hn = o_ * ftanh(cn);
                int node = i * 16 + quad * 4 + r;
                h0w[node * 128 + (((uch ^ (node & 15)) << 3) | ulo)] = (f16)hn;
            }
            c0s[i] = cc;
        }
        __syncthreads();   // barrier 1: h0_new visible to L1 readers

        // ======== layer 1: K = [h0_new(128) | h1(128)], NKT=8 ========
        #pragma unroll
        for (int i = 0; i < 2; ++i)
            #pragma unroll
            for (int g = 0; g < 4; ++g) acc[i][g] = (f32x4){0.f, 0.f, 0.f, 0.f};

        {
            int ktmax = (t == 0) ? 4 : 8;          // h1 zero at t=0
            #pragma unroll 2
            for (int kt = 0; kt < ktmax; ++kt) {
                const f16* hb = (kt < 4) ? h0w : h1r;   // h0_new | h1_old
                int ub = (kt & 3) * 4 + quad;
                f16x8 af[2];
                #pragma unroll
                for (int i = 0; i < 2; ++i)
                    af[i] = *(const f16x8*)&hb[(i * 16 + l) * 128 + ((ub ^ l) << 3)];
                const f16* bp = W1S + ((size_t)(uq * 8 + kt) * 4) * 512 + lane * 8;
                #pragma unroll
                for (int g = 0; g < 4; ++g) {
                    f16x8 b = *(const f16x8*)(bp + g * 512);
                    #pragma unroll
                    for (int i = 0; i < 2; ++i)
                        acc[i][g] = __builtin_amdgcn_mfma_f32_16x16x32_f16(af[i], b, acc[i][g], 0, 0, 0);
                }
            }
        }
        // L1 epilogue -> write h1_new into the OTHER buffer
        #pragma unroll
        for (int i = 0; i < 2; ++i) {
            f32x4 cc = c1s[i];
            #pragma unroll
            for (int r = 0; r < 4; ++r) {
                float i_ = fsig(acc[i][0][r] + bI1);
                float f_ = fsig(acc[i][1][r] + bF1);
                float g_ = ftanh(acc[i][2][r] + bG1);
                float o_ = fsig(acc[i][3][r] + bO1);
                float cn = f_ * cc[r] + i_ * g_;
                cc[r] = cn;
                float hn = o_ * ftanh(cn);
                int node = i * 16 + quad * 4 + r;
                h1w[node * 128 + (((uch ^ (node & 15)) << 3) | ulo)] = (f16)hn;
            }
            c1s[i] = cc;
        }
        __syncthreads();   // barrier 2: h1_new visible to next step's readers
    }

    // ======== head: out = x[:,4] + relu(h1@pw1.T+pb1)@pw2.T + pb2 ========
    // last step (t=4, cur=0) wrote h1buf[1]; waves 0..1 handle 16 nodes each
    const f16* h1f = h1buf[(Tt - 1) & 1 ? 0 : 1];   // Tt=5 -> h1buf[1]
    if (uq < 2) {
        f32x4 hacc[4];
        #pragma unroll
        for (int g = 0; g < 4; ++g) hacc[g] = (f32x4){0.f, 0.f, 0.f, 0.f};
        #pragma unroll
        for (int kt = 0; kt < 4; ++kt) {
            int ub = kt * 4 + quad;
            f16x8 a = *(const f16x8*)&h1f[(uq * 16 + l) * 128 + ((ub ^ l) << 3)];
            #pragma unroll
            for (int g = 0; g < 4; ++g) {
                f16x8 b = *(const f16x8*)(pwS + (size_t)(g * 4 + kt) * 512 + lane * 8);
                hacc[g] = __builtin_amdgcn_mfma_f32_16x16x32_f16(a, b, hacc[g], 0, 0, 0);
            }
        }
        float yr[4] = {0.f, 0.f, 0.f, 0.f};
        #pragma unroll
        for (int g = 0; g < 4; ++g) {
            float pb = pb1[g * 16 + l];
            float pw = pw2[g * 16 + l];
            #pragma unroll
            for (int r = 0; r < 4; ++r)
                yr[r] += fmaxf(hacc[g][r] + pb, 0.f) * pw;
        }
        #pragma unroll
        for (int m = 1; m <= 8; m <<= 1) {
            #pragma unroll
            for (int r = 0; r < 4; ++r) yr[r] += __shfl_xor(yr[r], m);
        }
        if (l < 4) {
            float v = (l == 0) ? yr[0] : (l == 1) ? yr[1] : (l == 2) ? yr[2] : yr[3];
            int node = n0 + uq * 16 + quad * 4 + l;
            out[node] = x[node * Tt + (Tt - 1)] + v + pb2[0];
        }
    }
}

extern "C" void kernel_launch(void* const* d_in, const int* in_sizes, int n_in,
                              void* d_out, int out_size, void* d_ws, size_t ws_size,
                              hipStream_t stream) {
    const float* x      = (const float*)d_in[0];
    const int*   ei     = (const int*)d_in[1];
    const float* gcn_w  = (const float*)d_in[2];
    const float* gcn_b  = (const float*)d_in[3];
    const float* w_ih0  = (const float*)d_in[4];
    const float* w_hh0  = (const float*)d_in[5];
    const float* b_ih0  = (const float*)d_in[6];
    const float* b_hh0  = (const float*)d_in[7];
    const float* w_ih1  = (const float*)d_in[8];
    const float* w_hh1  = (const float*)d_in[9];
    const float* b_ih1  = (const float*)d_in[10];
    const float* b_hh1  = (const float*)d_in[11];
    const float* pw1    = (const float*)d_in[12];
    const float* pb1    = (const float*)d_in[13];
    const float* pw2    = (const float*)d_in[14];
    const float* pb2    = (const float*)d_in[15];
    float* out = (float*)d_out;

    float* wsf  = (float*)d_ws;
    float* dinv = wsf + OFF_DINV;
    float* agg  = wsf + OFF_AGG;
    float* aggr = wsf + OFF_AGGR;
    int*   degr = (int*)(wsf + OFF_DEGR);
    float* B0   = wsf + OFF_B0;
    float* B1   = wsf + OFF_B1;
    f16*   W0S  = (f16*)(wsf + OFF_W0S);
    f16*   W1S  = (f16*)(wsf + OFF_W1S);
    f16*   pwS  = (f16*)(wsf + OFF_PWS);

    // 1) prep weights (swizzled f16, incl. head pw1) + fold biases + zero deg replicas
    prep_weights<<<1592, 256, 0, stream>>>(w_ih0, w_hh0, b_ih0, b_hh0,
                                           w_ih1, w_hh1, b_ih1, b_hh1, pw1,
                                           W0S, W1S, pwS, B0, B1, degr);
    // 2) degree (XCD-local atomics)
    deg_count<<<(Ee + 255) / 256, 256, 0, stream>>>(ei, degr);
    // 3) dinv + agg replica init
    agg_init<<<(Nn + 255) / 256, 256, 0, stream>>>(x, degr, dinv, aggr);
    // 4) edge scatter: one (edge,t) per thread, XCD-local atomics
    edge_scatter<<<(Ee * Tt + 255) / 256, 256, 0, stream>>>(x, ei, dinv, aggr);
    // 5) fold replicas (+ transpose agg to [t][n])
    agg_reduce<<<(Nn + 255) / 256, 256, 0, stream>>>(aggr, agg);

    // 6) fused recurrence: all LSTM steps + head, one dispatch (8-wave, 32-node blocks)
    recur_all<<<Nn / 32, 512, 0, stream>>>(agg, gcn_w, gcn_b, W0S, W1S, B0, B1,
                                           pwS, pb1, pw2, pb2, x, out);
}